// Round 7
// baseline (3470.329 us; speedup 1.0000x reference)
//
#include <hip/hip_runtime.h>
#include <math.h>

#define NW     64        // workgroups (proven co-resident)
#define NT     256       // threads per workgroup
#define H      256
#define CTX    128
#define V      33
#define T      220
#define BATCH  1024
#define SENT   0xAAAAAAAAu   // harness poison pattern; our sentinel
                             // (collision with real h-values empirically excluded in r4)

// ---- workspace layout (float offsets) ----
// [0..63]   startup counter (u32) + pad
#define WS_H0  64                    // [T][H] h0_t exchange
#define WS_H1  (WS_H0 + T*H)         // [T][H] h1_t
#define WS_H2  (WS_H1 + T*H)         // [T][H] h2_t
#define WS_PR  (WS_H2 + T*H)         // [T][V] compact predictions

__device__ __forceinline__ float gld(const float* p) {
  return __hip_atomic_load(p, __ATOMIC_RELAXED, __HIP_MEMORY_SCOPE_AGENT);
}
__device__ __forceinline__ void gst(float* p, float v) {
  __hip_atomic_store(p, v, __ATOMIC_RELAXED, __HIP_MEMORY_SCOPE_AGENT);
}
__device__ __forceinline__ float sigf(float x) { return 1.f / (1.f + expf(-x)); }

__device__ __forceinline__ float red16(float a) {
  #pragma unroll
  for (int m = 8; m; m >>= 1) a += __shfl_xor(a, m, 16);
  return a;
}

// dot of 16 register-resident weights with x[lane16*16 .. +16) from LDS
__device__ __forceinline__ float dot16s(const float4* __restrict__ w,
                                        const float* __restrict__ xsh, int lane16) {
  const float4* x4 = reinterpret_cast<const float4*>(xsh) + lane16 * 4;
  float a = 0.f;
  #pragma unroll
  for (int m = 0; m < 4; ++m) {
    float4 W = w[m], X = x4[m];
    a += W.x * X.x + W.y * X.y + W.z * X.z + W.w * X.w;
  }
  return a;
}

// poll one word until it is no longer the sentinel; returns the data. (r4-proven)
__device__ __forceinline__ float pollw(const float* p) {
  float v = gld(p);
  while (__float_as_uint(v) == SENT) v = gld(p);
  return v;
}

__global__ __launch_bounds__(NT, 1) void speller_persistent(
    const float* __restrict__ embed,     // [V][H]
    const float* __restrict__ Wih0,      // [4H][H+CTX]
    const float* __restrict__ Wih_rest,  // [2][4H][H]
    const float* __restrict__ Whh,       // [3][4H][H]
    const float* __restrict__ bih,       // [3][4H]
    const float* __restrict__ bhh,       // [3][4H]
    const float* __restrict__ W1,        // [H][H+CTX]
    const float* __restrict__ b1,        // [H]
    const float* __restrict__ W2,        // [V][H]
    const float* __restrict__ b2,        // [V]
    const float* __restrict__ h0,        // [3][H]
    const float* __restrict__ c0,        // [3][H]
    float* __restrict__ ws)
{
  __shared__ __align__(16) float sh_w[V * H];      // embed (prologue) then W2 (loop)
  __shared__ __align__(16) float sh_h0p[H];        // h0 state (LDS-retained)
  __shared__ __align__(16) float sh_h1p[H];
  __shared__ __align__(16) float sh_h2p[H];
  __shared__ __align__(16) float sh_f[H];          // classifier hidden (local)
  __shared__ float sh_tab[V * 16];                 // EMB slice for this WG's 16 rows
  __shared__ float sh_b1[H];
  __shared__ float sh_b2v[V];
  __shared__ float sh_logits[V];
  __shared__ int   sh_char;

  const int tid = threadIdx.x, wg = blockIdx.x;
  // LSTM mapping: wave jj owns h-index wg*4+jj; within wave: gate = l>>4, lane16 = l&15
  const int jj = tid >> 6, l = tid & 63, gate = l >> 4, lane16 = l & 15;
  const int hidx = wg * 4 + jj;
  const int wrow = gate * H + hidx;                // gate-row index in [0,1024)
  // classifier mapping: 16 rows x 16 lanes
  const int rr = tid >> 4, ll = tid & 15;

  unsigned* cnt = reinterpret_cast<unsigned*>(ws);
  float* HX0 = ws + WS_H0;
  float* HX1 = ws + WS_H1;
  float* HX2 = ws + WS_H2;
  float* PR  = ws + WS_PR;

  // ---- register-resident LSTM weights: 16 cols of this thread's gate-row ----
  float4 w_hh0[4], w_ih1[4], w_hh1[4], w_ih2[4], w_hh2[4];
  {
    const float4* p;
    p = reinterpret_cast<const float4*>(Whh + (size_t)wrow * H) + lane16 * 4;
    w_hh0[0]=p[0]; w_hh0[1]=p[1]; w_hh0[2]=p[2]; w_hh0[3]=p[3];
    p = reinterpret_cast<const float4*>(Wih_rest + (size_t)wrow * H) + lane16 * 4;
    w_ih1[0]=p[0]; w_ih1[1]=p[1]; w_ih1[2]=p[2]; w_ih1[3]=p[3];
    p = reinterpret_cast<const float4*>(Whh + (size_t)(1024 + wrow) * H) + lane16 * 4;
    w_hh1[0]=p[0]; w_hh1[1]=p[1]; w_hh1[2]=p[2]; w_hh1[3]=p[3];
    p = reinterpret_cast<const float4*>(Wih_rest + (size_t)(1024 + wrow) * H) + lane16 * 4;
    w_ih2[0]=p[0]; w_ih2[1]=p[1]; w_ih2[2]=p[2]; w_ih2[3]=p[3];
    p = reinterpret_cast<const float4*>(Whh + (size_t)(2048 + wrow) * H) + lane16 * 4;
    w_hh2[0]=p[0]; w_hh2[1]=p[1]; w_hh2[2]=p[2]; w_hh2[3]=p[3];
  }
  const float bsum1 = bih[1024 + wrow] + bhh[1024 + wrow];
  const float bsum2 = bih[2048 + wrow] + bhh[2048 + wrow];

  // ---- W1 fully replicated in registers: thread (rr,ll) holds rows p*16+rr,
  //      cols ll*16..ll*16+15 — 64 float4 = 256 VGPRs ----
  float4 w1c[16][4];
  #pragma unroll
  for (int p = 0; p < 16; ++p) {
    const float4* q = reinterpret_cast<const float4*>(
        W1 + (size_t)(p * 16 + rr) * (H + CTX)) + ll * 4;
    w1c[p][0]=q[0]; w1c[p][1]=q[1]; w1c[p][2]=q[2]; w1c[p][3]=q[3];
  }

  // per-wave c state (wave-uniform registers, all lanes redundant)
  float c0r = c0[0 * H + hidx];
  float c1r = c0[1 * H + hidx];
  float c2r = c0[2 * H + hidx];

  // LDS-retained h state init
  sh_h0p[tid] = h0[0 * H + tid];
  sh_h1p[tid] = h0[1 * H + tid];
  sh_h2p[tid] = h0[2 * H + tid];
  sh_b1[tid]  = b1[tid];
  if (tid < V) sh_b2v[tid] = b2[tid];

  // ---- prologue A: embed into LDS, compute per-WG EMB table ----
  for (int i = tid; i < V * H; i += NT) sh_w[i] = embed[i];
  __syncthreads();
  {
    const float4* w4 = reinterpret_cast<const float4*>(
        Wih0 + (size_t)wrow * (H + CTX) + lane16 * 16);
    const float4 q0 = w4[0], q1 = w4[1], q2 = w4[2], q3 = w4[3];
    const float bs = bih[wrow] + bhh[wrow];
    for (int v = 0; v < V; ++v) {
      const float4* e4 = reinterpret_cast<const float4*>(sh_w + v * H + lane16 * 16);
      float4 e0 = e4[0], e1 = e4[1], e2 = e4[2], e3 = e4[3];
      float a = q0.x*e0.x + q0.y*e0.y + q0.z*e0.z + q0.w*e0.w
              + q1.x*e1.x + q1.y*e1.y + q1.z*e1.z + q1.w*e1.w
              + q2.x*e2.x + q2.y*e2.y + q2.z*e2.z + q2.w*e2.w
              + q3.x*e3.x + q3.y*e3.y + q3.z*e3.z + q3.w*e3.w;
      a = red16(a);
      if (lane16 == 0) sh_tab[v * 16 + gate * 4 + jj] = a + bs;
    }
  }
  __syncthreads();
  // ---- prologue B: overwrite sh_w with W2 ----
  for (int i = tid; i < V * H; i += NT) sh_w[i] = W2[i];

  // ---- prologue C: poison this WG's producer slots for all t ----
  if (tid < T) {
    const float sf = __uint_as_float(SENT);
    #pragma unroll
    for (int k = 0; k < 4; ++k) {
      gst(HX0 + (size_t)tid * H + wg * 4 + k, sf);
      gst(HX1 + (size_t)tid * H + wg * 4 + k, sf);
      gst(HX2 + (size_t)tid * H + wg * 4 + k, sf);
    }
  }

  // ---- one startup barrier (proven counter barrier) ----
  __syncthreads();
  if (tid == 0) {
    __hip_atomic_fetch_add(cnt, 1u, __ATOMIC_RELEASE, __HIP_MEMORY_SCOPE_AGENT);
    while (__hip_atomic_load(cnt, __ATOMIC_ACQUIRE, __HIP_MEMORY_SCOPE_AGENT)
           < (unsigned)NW)
      __builtin_amdgcn_s_sleep(8);
  }
  __syncthreads();

  // redundant local classifier: f = relu(W1.h2 + b1) -> logits (all in LDS)
  auto classify = [&]() {
    const float4* x4 = reinterpret_cast<const float4*>(sh_h2p) + ll * 4;
    const float4 X0 = x4[0], X1 = x4[1], X2 = x4[2], X3 = x4[3];
    #pragma unroll
    for (int p = 0; p < 16; ++p) {
      float a = 0.f;
      a += w1c[p][0].x*X0.x + w1c[p][0].y*X0.y + w1c[p][0].z*X0.z + w1c[p][0].w*X0.w;
      a += w1c[p][1].x*X1.x + w1c[p][1].y*X1.y + w1c[p][1].z*X1.z + w1c[p][1].w*X1.w;
      a += w1c[p][2].x*X2.x + w1c[p][2].y*X2.y + w1c[p][2].z*X2.z + w1c[p][2].w*X2.w;
      a += w1c[p][3].x*X3.x + w1c[p][3].y*X3.y + w1c[p][3].z*X3.z + w1c[p][3].w*X3.w;
      a = red16(a);
      if (ll == 0) sh_f[p * 16 + rr] = fmaxf(a + sh_b1[p * 16 + rr], 0.f);
    }
    __syncthreads();
    const int v = tid >> 2, s = tid & 3;          // 4 lanes per logit
    if (v < V) {
      const float4* wv = reinterpret_cast<const float4*>(sh_w + v * H) + s * 16;
      const float4* fv = reinterpret_cast<const float4*>(sh_f) + s * 16;
      float a = 0.f;
      #pragma unroll
      for (int m = 0; m < 16; ++m) {
        float4 Wq = wv[m], Fq = fv[m];
        a += Wq.x*Fq.x + Wq.y*Fq.y + Wq.z*Fq.z + Wq.w*Fq.w;
      }
      a += __shfl_xor(a, 1, 4);
      a += __shfl_xor(a, 2, 4);
      if (s == 0) sh_logits[v] = a + sh_b2v[v];
    }
    __syncthreads();
  };

  // gate combine: gather 4 gate values across the wave, update c, return h
  auto lstm_h = [&](float a, float& creg) -> float {
    float gi = __shfl(a,  0, 64);
    float gf = __shfl(a, 16, 64);
    float gg = __shfl(a, 32, 64);
    float go = __shfl(a, 48, 64);
    float cn = sigf(gf) * creg + sigf(gi) * tanhf(gg);
    creg = cn;
    return sigf(go) * tanhf(cn);
  };

  // L0 hh-dot for t=0 (char-free part, uses h0 init)
  float a0 = red16(dot16s(w_hh0, sh_h0p, lane16));

  for (int t = 0; t < T; ++t) {
    // ===== phase 0 (local): classifier(t-1) + argmax =====
    int chr = 0;
    if (t > 0) {
      classify();                                  // logits(t-1) from sh_h2p
      if (tid < 64) {                              // wave-parallel first-max argmax
        float bv = (tid < V) ? sh_logits[tid] : -1e30f;
        int   bi = tid;
        #pragma unroll
        for (int m = 32; m; m >>= 1) {
          float ov = __shfl_xor(bv, m, 64);
          int   oi = __shfl_xor(bi, m, 64);
          if (ov > bv || (ov == bv && oi < bi)) { bv = ov; bi = oi; }
        }
        if (tid == 0) sh_char = bi;
      }
      __syncthreads();
      chr = sh_char;
      if (wg == 0 && tid < V) PR[(size_t)(t - 1) * V + tid] = sh_logits[tid];
    }

    // ===== phase 1: L0 publish (no LDS round in gate path) =====
    {
      float a = a0 + sh_tab[chr * 16 + gate * 4 + jj];
      float hv = lstm_h(a, c0r);
      if (l == 0) gst(HX0 + (size_t)t * H + hidx, hv);
    }

    // ===== phase 2: hh1-dot early; poll h0_t; L1 publish =====
    float a1h = dot16s(w_hh1, sh_h1p, lane16);     // h1_{t-1} (pre-poll)
    sh_h0p[tid] = pollw(HX0 + (size_t)t * H + tid);
    __syncthreads();
    {
      float a = red16(a1h + dot16s(w_ih1, sh_h0p, lane16)) + bsum1;
      float hv = lstm_h(a, c1r);
      if (l == 0) gst(HX1 + (size_t)t * H + hidx, hv);
    }

    // ===== phase 3: hh2-dot early; poll h1_t; L2 publish =====
    float a2h = dot16s(w_hh2, sh_h2p, lane16);     // h2_{t-1} (pre-poll)
    sh_h1p[tid] = pollw(HX1 + (size_t)t * H + tid);
    __syncthreads();
    {
      float a = red16(a2h + dot16s(w_ih2, sh_h1p, lane16)) + bsum2;
      float hv = lstm_h(a, c2r);
      if (l == 0) gst(HX2 + (size_t)t * H + hidx, hv);
    }

    // ===== phase 4: next-step L0 hh-dot early; poll h2_t =====
    a0 = red16(dot16s(w_hh0, sh_h0p, lane16));     // uses h0_t (for t+1)
    sh_h2p[tid] = pollw(HX2 + (size_t)t * H + tid);
    __syncthreads();
  }

  // ===== epilogue: logits(T-1), redundant; wg0 writes =====
  classify();
  if (wg == 0 && tid < V) PR[(size_t)(T - 1) * V + tid] = sh_logits[tid];
}

// broadcast compact [T][V] predictions to [B][T][V]
__global__ __launch_bounds__(NT) void bcast_kernel(const float* __restrict__ PR,
                                                   float* __restrict__ out) {
  float* o = out + (size_t)blockIdx.x * (T * V);
  for (int i = threadIdx.x; i < T * V; i += NT) o[i] = PR[i];
}

extern "C" void kernel_launch(void* const* d_in, const int* in_sizes, int n_in,
                              void* d_out, int out_size, void* d_ws, size_t ws_size,
                              hipStream_t stream) {
  const float* embed    = (const float*)d_in[1];
  const float* Wih0     = (const float*)d_in[2];
  const float* Wih_rest = (const float*)d_in[3];
  const float* Whh      = (const float*)d_in[4];
  const float* bih      = (const float*)d_in[5];
  const float* bhh      = (const float*)d_in[6];
  const float* W1       = (const float*)d_in[7];
  const float* b1       = (const float*)d_in[8];
  const float* W2       = (const float*)d_in[9];
  const float* b2       = (const float*)d_in[10];
  const float* h0       = (const float*)d_in[11];
  const float* c0       = (const float*)d_in[12];
  float* out = (float*)d_out;
  float* ws  = (float*)d_ws;

  // zero the startup counter (ws is poisoned 0xAA before every launch)
  hipMemsetAsync(d_ws, 0, 256, stream);

  speller_persistent<<<NW, NT, 0, stream>>>(embed, Wih0, Wih_rest, Whh, bih, bhh,
                                            W1, b1, W2, b2, h0, c0, ws);
  bcast_kernel<<<BATCH, NT, 0, stream>>>(ws + WS_PR, out);
}